// Round 7
// baseline (258.699 us; speedup 1.0000x reference)
//
#include <hip/hip_runtime.h>
#include <math.h>

#define B_ 2
#define DMODEL 128
#define DIN 256
#define DSTATE 16
#define DTR 8
#define OUTC 128
#define Lseq 4096
#define NC 512          // chunks per batch
#define LC 8            // timesteps per chunk

__device__ __forceinline__ float siluf(float x){ return x / (1.f + __expf(-x)); }

// zs  layout: float  at (b*Lseq + l)*DIN + d                  (planar, coalesced)
// pk2 layout: float2 {dt, xc} at (b*Lseq + l)*DIN + d         (written once, coalesced)
// BCp layout: BCp[(b*NC + c)*256 + l*32 + q], q<16: B else C  (l local 0..7)
// PSw layout: float2 at (b*NC + c)*4096 + d*16 + s
// Iw  layout: float  at (b*NC + c)*4096 + d*16 + s            (state entering chunk c)

// ---------------- Kernel A: in_proj; 1024 blocks = b x colhalf x 256 l-tiles of 16 ------------------------
__global__ __launch_bounds__(256, 4) void k_inproj(const float* __restrict__ x1,
        const float* __restrict__ Win, float* __restrict__ xin, float* __restrict__ zs){
    __shared__ float xt[16*DMODEL];             // xt[c*16+p]
    int blk = blockIdx.x;
    int b  = blk >> 9;
    int ch = (blk >> 8) & 1;                    // 0: xin cols, 1: z cols
    int lc = blk & 255;
    int l0 = lc * 16;
    int t = threadIdx.x;
    const float* xb = x1 + (size_t)b * DMODEL * Lseq;
    #pragma unroll
    for (int i = 0; i < 8; ++i){
        int e = t + i*256;
        int c = e >> 4, p = e & 15;
        xt[e] = xb[(size_t)c*Lseq + l0 + p];
    }
    __syncthreads();
    float acc[16];
    #pragma unroll
    for (int p=0;p<16;++p) acc[p]=0.f;
    const float* wcol = Win + ch*256 + t;
    for (int k=0;k<DMODEL;++k){
        float w = wcol[k*512];
        #pragma unroll
        for (int p=0;p<16;++p) acc[p] = fmaf(xt[k*16 + p], w, acc[p]);
    }
    if (ch == 0){
        #pragma unroll
        for (int p=0;p<16;++p)
            xin[((size_t)(b*Lseq + l0 + p))*DIN + t] = acc[p];
    } else {
        #pragma unroll
        for (int p=0;p<16;++p)
            zs[((size_t)(b*Lseq + l0 + p))*DIN + t] = siluf(acc[p]);
    }
}

// ---------------- Kernel B: conv+silu, x_proj (split-d), dt_proj, fused scan pass 1; 8 l per block --------
__global__ __launch_bounds__(256, 4) void k_conv_scan1(const float* __restrict__ xin,
        const float* __restrict__ convw, const float* __restrict__ convb,
        const float* __restrict__ Wx, const float* __restrict__ Wdt,
        const float* __restrict__ bdt, const float* __restrict__ Alog,
        float2* __restrict__ pk2, float* __restrict__ BCp, float2* __restrict__ PSw){
    __shared__ float xcs[LC*257];       // [l][d]
    __shared__ float part[4*LC*40];     // [dq][l][j]
    __shared__ float xdbl[LC*40];       // [l][j]
    int blk = blockIdx.x;               // 1024 = b x 512 chunks
    int b = blk >> 9, c = blk & 511;
    int l0 = c * LC;
    int t = threadIdx.x;                // = d in conv/dt/scan phases

    // ---- conv + silu: rows l0-3 .. l0+7 ----
    float w0 = convw[t*4+0], w1 = convw[t*4+1], w2 = convw[t*4+2], w3 = convw[t*4+3];
    float bb = convb[t];
    const float* xinb = xin + ((size_t)(b*Lseq + l0))*DIN + t;
    float r[11];
    if (l0 == 0){ r[0]=r[1]=r[2]=0.f; }
    else {
        r[0] = xinb[-3*DIN]; r[1] = xinb[-2*DIN]; r[2] = xinb[-1*DIN];
    }
    #pragma unroll
    for (int i=0;i<8;++i) r[3+i] = xinb[i*DIN];
    #pragma unroll
    for (int l=0;l<LC;++l){
        float acc = bb;
        acc = fmaf(r[l],   w0, acc);
        acc = fmaf(r[l+1], w1, acc);
        acc = fmaf(r[l+2], w2, acc);
        acc = fmaf(r[l+3], w3, acc);
        xcs[l*257 + t] = siluf(acc);
    }
    __syncthreads();

    // ---- x_proj with split-d: dq = quarter of d-range ----
    {
        int dq = t >> 6;
        int lg = (t >> 3) & 7;
        int jg = t & 7;
        int j0 = jg * 5;
        float a0=0.f, a1=0.f, a2=0.f, a3=0.f, a4=0.f;
        const float* xrow = xcs + lg*257 + dq*64;
        const float* wbase = Wx + (size_t)dq*64*40 + j0;
        #pragma unroll 8
        for (int dd = 0; dd < 64; ++dd){
            float xv = xrow[dd];
            const float* wr = wbase + dd*40;
            a0 = fmaf(xv, wr[0], a0);
            a1 = fmaf(xv, wr[1], a1);
            a2 = fmaf(xv, wr[2], a2);
            a3 = fmaf(xv, wr[3], a3);
            a4 = fmaf(xv, wr[4], a4);
        }
        float* po = part + dq*320 + lg*40 + j0;
        po[0]=a0; po[1]=a1; po[2]=a2; po[3]=a3; po[4]=a4;
    }
    __syncthreads();
    for (int o = t; o < 320; o += 256)
        xdbl[o] = part[o] + part[320+o] + part[640+o] + part[960+o];
    __syncthreads();

    // ---- dt_proj + softplus + scan pass 1 (one 8-l chunk); write {dt,xc} packed, coalesced ----
    {
        float wd[DTR];
        #pragma unroll
        for (int rr=0;rr<DTR;++rr) wd[rr] = Wdt[rr*DIN + t];
        float bv = bdt[t];
        float Av[16];
        {
            const float4* Ap = (const float4*)(Alog + t*DSTATE);
            #pragma unroll
            for (int q=0;q<4;++q){
                float4 a = Ap[q];
                Av[q*4]   = -__expf(a.x);
                Av[q*4+1] = -__expf(a.y);
                Av[q*4+2] = -__expf(a.z);
                Av[q*4+3] = -__expf(a.w);
            }
        }
        float P[16], S[16];
        #pragma unroll
        for (int s=0;s<16;++s){ P[s]=1.f; S[s]=0.f; }
        float2* pkb = pk2 + ((size_t)(b*Lseq + l0))*DIN + t;
        #pragma unroll
        for (int l=0;l<LC;++l){
            float a = bv;
            #pragma unroll
            for (int rr=0;rr<DTR;++rr) a = fmaf(xdbl[l*40 + rr], wd[rr], a);
            float dtv = (a > 20.f) ? a : log1pf(__expf(a));
            float xcv = xcs[l*257 + t];
            pkb[l*DIN] = make_float2(dtv, xcv);
            float dx  = dtv*xcv;
            const float4* Bv = (const float4*)&xdbl[l*40 + DTR];
            float4 B0 = Bv[0], B1 = Bv[1], B2 = Bv[2], B3 = Bv[3];
            #define ST1(i, bval) { float dA = __expf(dtv*Av[i]); P[i] *= dA; S[i] = fmaf(dA, S[i], dx*(bval)); }
            ST1(0,B0.x) ST1(1,B0.y) ST1(2,B0.z) ST1(3,B0.w)
            ST1(4,B1.x) ST1(5,B1.y) ST1(6,B1.z) ST1(7,B1.w)
            ST1(8,B2.x) ST1(9,B2.y) ST1(10,B2.z) ST1(11,B2.w)
            ST1(12,B3.x) ST1(13,B3.y) ST1(14,B3.z) ST1(15,B3.w)
            #undef ST1
        }
        float2* ps = PSw + ((size_t)(b*NC + c))*4096 + t*DSTATE;
        #pragma unroll
        for (int s=0;s<16;++s) ps[s] = make_float2(P[s], S[s]);
    }
    // ---- B/C extraction: 8 l x 32 ----
    {
        int l = t >> 5, q = t & 31;
        BCp[((size_t)(b*NC + c))*256 + t] = xdbl[l*40 + DTR + q];
    }
}

// ---------------- Kernel C: pass 2, serial chunk combine, coalesced streams -------------------------------
__global__ __launch_bounds__(256, 4) void k_scan2(const float2* __restrict__ PSw,
        float* __restrict__ Iw){
    int g = blockIdx.x*256 + threadIdx.x;  // 8192 channels
    int b = g >> 12;
    int r = g & 4095;
    float H = 0.f;
    #pragma unroll 8
    for (int c=0;c<NC;++c){
        size_t idx = ((size_t)(b*NC + c))*4096 + r;
        float2 ps = PSw[idx];
        Iw[idx] = H;
        H = fmaf(ps.x, H, ps.y);
    }
}

// ---------------- Kernel D: fused scan pass 3 + out_proj + LayerNorm + NCHW store; 8 l per block ----------
__global__ __launch_bounds__(256, 4) void k_scan3out(const float2* __restrict__ pk2,
        const float* __restrict__ zs,
        const float* __restrict__ BCp, const float* __restrict__ Alog,
        const float* __restrict__ Dv, const float* __restrict__ Iw,
        const float* __restrict__ Wout, const float* __restrict__ lng,
        const float* __restrict__ lnb, float* __restrict__ out){
    __shared__ float ysm[256*9 + 8];   // [d][l] stride 9
    __shared__ float os[128*9 + 8];    // [c][l] stride 9
    __shared__ float bc[256];          // [l][q]
    int blk = blockIdx.x;              // 1024 = b x 512 chunks
    int b = blk >> 9, c = blk & 511;
    int l0 = c * LC;
    int t = threadIdx.x;               // = d in scan phase
    bc[t] = BCp[((size_t)(b*NC + c))*256 + t];
    float Av[16];
    {
        const float4* Ap = (const float4*)(Alog + t*DSTATE);
        #pragma unroll
        for (int q=0;q<4;++q){
            float4 a = Ap[q];
            Av[q*4]   = -__expf(a.x);
            Av[q*4+1] = -__expf(a.y);
            Av[q*4+2] = -__expf(a.z);
            Av[q*4+3] = -__expf(a.w);
        }
    }
    float h[16];
    {
        const float4* Ip = (const float4*)(Iw + ((size_t)(b*NC + c))*4096 + t*DSTATE);
        #pragma unroll
        for (int q=0;q<4;++q){
            float4 v = Ip[q];
            h[q*4]=v.x; h[q*4+1]=v.y; h[q*4+2]=v.z; h[q*4+3]=v.w;
        }
    }
    // batched independent loads: 8 float2 (dt,xc) + 8 scalar z
    float2 dx2[LC];
    float  zv[LC];
    {
        const float2* pkb = pk2 + ((size_t)(b*Lseq + l0))*DIN + t;
        const float* zsp  = zs  + ((size_t)(b*Lseq + l0))*DIN + t;
        #pragma unroll
        for (int l=0;l<LC;++l){ dx2[l] = pkb[l*DIN]; zv[l] = zsp[l*DIN]; }
    }
    float Dd = Dv[t];
    __syncthreads();
    #pragma unroll
    for (int l=0;l<LC;++l){
        float dtl = dx2[l].x, xcv = dx2[l].y;
        float dx  = dtl*xcv;
        const float4* Bv = (const float4*)&bc[l*32];
        const float4* Cv = (const float4*)&bc[l*32 + 16];
        float4 B0 = Bv[0], B1 = Bv[1], B2 = Bv[2], B3 = Bv[3];
        float4 C0 = Cv[0], C1 = Cv[1], C2 = Cv[2], C3 = Cv[3];
        float y = 0.f;
        #define ST3(i, bval, cval) { float dA = __expf(dtl*Av[i]); h[i] = fmaf(dA, h[i], dx*(bval)); y = fmaf(h[i], (cval), y); }
        ST3(0,B0.x,C0.x) ST3(1,B0.y,C0.y) ST3(2,B0.z,C0.z) ST3(3,B0.w,C0.w)
        ST3(4,B1.x,C1.x) ST3(5,B1.y,C1.y) ST3(6,B1.z,C1.z) ST3(7,B1.w,C1.w)
        ST3(8,B2.x,C2.x) ST3(9,B2.y,C2.y) ST3(10,B2.z,C2.z) ST3(11,B2.w,C2.w)
        ST3(12,B3.x,C3.x) ST3(13,B3.y,C3.y) ST3(14,B3.z,C3.z) ST3(15,B3.w,C3.w)
        #undef ST3
        ysm[t*9 + l] = (y + Dd*xcv)*zv[l];
    }
    __syncthreads();
    // ---- out_proj: 8l x 128c tile. lg = t>>5 -> one l; cg = t&31 -> 4 c ----
    int lg = t >> 5, cg = t & 31;
    int c0 = cg*4;
    float a0=0.f, a1=0.f, a2=0.f, a3=0.f;
    #pragma unroll 8
    for (int k=0;k<DIN;++k){
        float yv = ysm[k*9 + lg];
        float4 wv = *(const float4*)&Wout[k*OUTC + c0];
        a0 = fmaf(yv, wv.x, a0);
        a1 = fmaf(yv, wv.y, a1);
        a2 = fmaf(yv, wv.z, a2);
        a3 = fmaf(yv, wv.w, a3);
    }
    float4 gm = *(const float4*)&lng[c0];
    float4 bt = *(const float4*)&lnb[c0];
    {
        float rs = a0+a1+a2+a3;
        #pragma unroll
        for (int m=16;m>0;m>>=1) rs += __shfl_xor(rs, m, 64);
        float mu = rs * (1.f/128.f);
        float d0 = a0-mu, d1 = a1-mu, d2 = a2-mu, d3 = a3-mu;
        float sq = d0*d0+d1*d1+d2*d2+d3*d3;
        #pragma unroll
        for (int m=16;m>0;m>>=1) sq += __shfl_xor(sq, m, 64);
        float rstd = rsqrtf(sq * (1.f/128.f) + 1e-5f);
        os[(c0+0)*9 + lg] = d0*rstd*gm.x + bt.x;
        os[(c0+1)*9 + lg] = d1*rstd*gm.y + bt.y;
        os[(c0+2)*9 + lg] = d2*rstd*gm.z + bt.z;
        os[(c0+3)*9 + lg] = d3*rstd*gm.w + bt.w;
    }
    __syncthreads();
    // ---- store: cc = t>>1, sel = t&1 -> 4 consecutive l (16B) per lane ----
    {
        int cc = t >> 1, sel = t & 1;
        const float* ip = &os[cc*9 + sel*4];
        float v0 = ip[0], v1 = ip[1], v2 = ip[2], v3 = ip[3];
        float* op = out + ((size_t)(b*OUTC + cc))*Lseq + l0 + sel*4;
        *(float4*)op = make_float4(v0, v1, v2, v3);
    }
}

extern "C" void kernel_launch(void* const* d_in, const int* in_sizes, int n_in,
                              void* d_out, int out_size, void* d_ws, size_t ws_size,
                              hipStream_t stream) {
    const float* x1    = (const float*)d_in[0];
    const float* Win   = (const float*)d_in[1];
    const float* convw = (const float*)d_in[2];
    const float* convb = (const float*)d_in[3];
    const float* Wx    = (const float*)d_in[4];
    const float* Wdt   = (const float*)d_in[5];
    const float* bdt   = (const float*)d_in[6];
    const float* Alog  = (const float*)d_in[7];
    const float* Dv    = (const float*)d_in[8];
    const float* Wout  = (const float*)d_in[9];
    const float* lng   = (const float*)d_in[10];
    const float* lnb   = (const float*)d_in[11];
    float* out = (float*)d_out;

    float* ws  = (float*)d_ws;
    float* xin = ws;                        // 2,097,152 floats (8 MB)
    float* zs  = xin + 2097152;             // 2,097,152 floats (8 MB)
    float2* pk2 = (float2*)(zs + 2097152);  // 2,097,152 float2 (16 MB): {dt, xc}
    float2* PSw = (float2*)(pk2 + 2097152); // 4,194,304 float2 (32 MB)
    float* Iw  = (float*)(PSw + 4194304);   // 4,194,304 floats (16 MB)
    float* BCp = Iw + 4194304;              //   262,144 floats (1 MB)   total ~81 MB

    k_inproj    <<<1024, 256, 0, stream>>>(x1, Win, xin, zs);
    k_conv_scan1<<<1024, 256, 0, stream>>>(xin, convw, convb, Wx, Wdt, bdt, Alog,
                                           pk2, BCp, PSw);
    k_scan2     <<<32,   256, 0, stream>>>(PSw, Iw);
    k_scan3out  <<<1024, 256, 0, stream>>>(pk2, zs, BCp, Alog, Dv, Iw,
                                           Wout, lng, lnb, out);
}

// Round 8
// 244.607 us; speedup vs baseline: 1.0576x; 1.0576x over previous
//
#include <hip/hip_runtime.h>
#include <math.h>

#define B_ 2
#define DMODEL 128
#define DIN 256
#define DSTATE 16
#define DTR 8
#define OUTC 128
#define Lseq 4096
#define NC 512          // chunks per batch
#define LC 8            // timesteps per chunk

__device__ __forceinline__ float siluf(float x){ return x / (1.f + __expf(-x)); }

// zs  layout: float  at (b*Lseq + l)*DIN + d                  (planar, coalesced)
// pk2 layout: float2 {dt, xc} at (b*Lseq + l)*DIN + d         (written once, coalesced)
// BCp layout: BCp[(b*NC + c)*256 + l*32 + q], q<16: B else C  (l local 0..7)
// PSw layout: float2 at (b*NC + c)*4096 + s*256 + d           (s-major: full-line stores)
// Iw  layout: float  at (b*NC + c)*4096 + s*256 + d           (state entering chunk c)

// ---------------- Kernel A: in_proj; 1024 blocks = b x colhalf x 256 l-tiles of 16 ------------------------
__global__ __launch_bounds__(256, 4) void k_inproj(const float* __restrict__ x1,
        const float* __restrict__ Win, float* __restrict__ xin, float* __restrict__ zs){
    __shared__ float xt[16*DMODEL];             // xt[c*16+p]
    int blk = blockIdx.x;
    int b  = blk >> 9;
    int ch = (blk >> 8) & 1;                    // 0: xin cols, 1: z cols
    int lc = blk & 255;
    int l0 = lc * 16;
    int t = threadIdx.x;
    const float* xb = x1 + (size_t)b * DMODEL * Lseq;
    #pragma unroll
    for (int i = 0; i < 8; ++i){
        int e = t + i*256;
        int c = e >> 4, p = e & 15;
        xt[e] = xb[(size_t)c*Lseq + l0 + p];
    }
    __syncthreads();
    float acc[16];
    #pragma unroll
    for (int p=0;p<16;++p) acc[p]=0.f;
    const float* wcol = Win + ch*256 + t;
    for (int k=0;k<DMODEL;++k){
        float w = wcol[k*512];
        #pragma unroll
        for (int p=0;p<16;++p) acc[p] = fmaf(xt[k*16 + p], w, acc[p]);
    }
    if (ch == 0){
        #pragma unroll
        for (int p=0;p<16;++p)
            xin[((size_t)(b*Lseq + l0 + p))*DIN + t] = acc[p];
    } else {
        #pragma unroll
        for (int p=0;p<16;++p)
            zs[((size_t)(b*Lseq + l0 + p))*DIN + t] = siluf(acc[p]);
    }
}

// ---------------- Kernel B: conv+silu, x_proj (split-d), dt_proj, fused scan pass 1; 8 l per block --------
__global__ __launch_bounds__(256, 4) void k_conv_scan1(const float* __restrict__ xin,
        const float* __restrict__ convw, const float* __restrict__ convb,
        const float* __restrict__ Wx, const float* __restrict__ Wdt,
        const float* __restrict__ bdt, const float* __restrict__ Alog,
        float2* __restrict__ pk2, float* __restrict__ BCp, float2* __restrict__ PSw){
    __shared__ float xcs[LC*257];       // [l][d]
    __shared__ float part[4*LC*40];     // [dq][l][j]
    __shared__ float xdbl[LC*40];       // [l][j]
    int blk = blockIdx.x;               // 1024 = b x 512 chunks
    int b = blk >> 9, c = blk & 511;
    int l0 = c * LC;
    int t = threadIdx.x;                // = d in conv/dt/scan phases

    // ---- conv + silu: rows l0-3 .. l0+7 ----
    float w0 = convw[t*4+0], w1 = convw[t*4+1], w2 = convw[t*4+2], w3 = convw[t*4+3];
    float bb = convb[t];
    const float* xinb = xin + ((size_t)(b*Lseq + l0))*DIN + t;
    float r[11];
    if (l0 == 0){ r[0]=r[1]=r[2]=0.f; }
    else {
        r[0] = xinb[-3*DIN]; r[1] = xinb[-2*DIN]; r[2] = xinb[-1*DIN];
    }
    #pragma unroll
    for (int i=0;i<8;++i) r[3+i] = xinb[i*DIN];
    #pragma unroll
    for (int l=0;l<LC;++l){
        float acc = bb;
        acc = fmaf(r[l],   w0, acc);
        acc = fmaf(r[l+1], w1, acc);
        acc = fmaf(r[l+2], w2, acc);
        acc = fmaf(r[l+3], w3, acc);
        xcs[l*257 + t] = siluf(acc);
    }
    __syncthreads();

    // ---- x_proj with split-d: dq = quarter of d-range ----
    {
        int dq = t >> 6;
        int lg = (t >> 3) & 7;
        int jg = t & 7;
        int j0 = jg * 5;
        float a0=0.f, a1=0.f, a2=0.f, a3=0.f, a4=0.f;
        const float* xrow = xcs + lg*257 + dq*64;
        const float* wbase = Wx + (size_t)dq*64*40 + j0;
        #pragma unroll 8
        for (int dd = 0; dd < 64; ++dd){
            float xv = xrow[dd];
            const float* wr = wbase + dd*40;
            a0 = fmaf(xv, wr[0], a0);
            a1 = fmaf(xv, wr[1], a1);
            a2 = fmaf(xv, wr[2], a2);
            a3 = fmaf(xv, wr[3], a3);
            a4 = fmaf(xv, wr[4], a4);
        }
        float* po = part + dq*320 + lg*40 + j0;
        po[0]=a0; po[1]=a1; po[2]=a2; po[3]=a3; po[4]=a4;
    }
    __syncthreads();
    for (int o = t; o < 320; o += 256)
        xdbl[o] = part[o] + part[320+o] + part[640+o] + part[960+o];
    __syncthreads();

    // ---- dt_proj + softplus + scan pass 1 (one 8-l chunk); write {dt,xc} packed, coalesced ----
    {
        float wd[DTR];
        #pragma unroll
        for (int rr=0;rr<DTR;++rr) wd[rr] = Wdt[rr*DIN + t];
        float bv = bdt[t];
        float Av[16];
        {
            const float4* Ap = (const float4*)(Alog + t*DSTATE);
            #pragma unroll
            for (int q=0;q<4;++q){
                float4 a = Ap[q];
                Av[q*4]   = -__expf(a.x);
                Av[q*4+1] = -__expf(a.y);
                Av[q*4+2] = -__expf(a.z);
                Av[q*4+3] = -__expf(a.w);
            }
        }
        float P[16], S[16];
        #pragma unroll
        for (int s=0;s<16;++s){ P[s]=1.f; S[s]=0.f; }
        float2* pkb = pk2 + ((size_t)(b*Lseq + l0))*DIN + t;
        #pragma unroll
        for (int l=0;l<LC;++l){
            float a = bv;
            #pragma unroll
            for (int rr=0;rr<DTR;++rr) a = fmaf(xdbl[l*40 + rr], wd[rr], a);
            float dtv = (a > 20.f) ? a : log1pf(__expf(a));
            float xcv = xcs[l*257 + t];
            pkb[l*DIN] = make_float2(dtv, xcv);
            float dx  = dtv*xcv;
            const float4* Bv = (const float4*)&xdbl[l*40 + DTR];
            float4 B0 = Bv[0], B1 = Bv[1], B2 = Bv[2], B3 = Bv[3];
            #define ST1(i, bval) { float dA = __expf(dtv*Av[i]); P[i] *= dA; S[i] = fmaf(dA, S[i], dx*(bval)); }
            ST1(0,B0.x) ST1(1,B0.y) ST1(2,B0.z) ST1(3,B0.w)
            ST1(4,B1.x) ST1(5,B1.y) ST1(6,B1.z) ST1(7,B1.w)
            ST1(8,B2.x) ST1(9,B2.y) ST1(10,B2.z) ST1(11,B2.w)
            ST1(12,B3.x) ST1(13,B3.y) ST1(14,B3.z) ST1(15,B3.w)
            #undef ST1
        }
        // s-major, full-line coalesced stores: 512B contiguous per wave per s
        float2* ps = PSw + ((size_t)(b*NC + c))*4096 + t;
        #pragma unroll
        for (int s=0;s<16;++s) ps[s*256] = make_float2(P[s], S[s]);
    }
    // ---- B/C extraction: 8 l x 32 ----
    {
        int l = t >> 5, q = t & 31;
        BCp[((size_t)(b*NC + c))*256 + t] = xdbl[l*40 + DTR + q];
    }
}

// ---------------- Kernel C: pass 2, serial chunk combine, coalesced streams -------------------------------
__global__ __launch_bounds__(256, 4) void k_scan2(const float2* __restrict__ PSw,
        float* __restrict__ Iw){
    int g = blockIdx.x*256 + threadIdx.x;  // 8192 channels
    int b = g >> 12;
    int r = g & 4095;
    float H = 0.f;
    #pragma unroll 8
    for (int c=0;c<NC;++c){
        size_t idx = ((size_t)(b*NC + c))*4096 + r;
        float2 ps = PSw[idx];
        Iw[idx] = H;
        H = fmaf(ps.x, H, ps.y);
    }
}

// ---------------- Kernel D: fused scan pass 3 + out_proj + LayerNorm + NCHW store; 8 l per block ----------
__global__ __launch_bounds__(256, 4) void k_scan3out(const float2* __restrict__ pk2,
        const float* __restrict__ zs,
        const float* __restrict__ BCp, const float* __restrict__ Alog,
        const float* __restrict__ Dv, const float* __restrict__ Iw,
        const float* __restrict__ Wout, const float* __restrict__ lng,
        const float* __restrict__ lnb, float* __restrict__ out){
    __shared__ float ysm[256*9 + 8];   // [d][l] stride 9
    __shared__ float os[128*9 + 8];    // [c][l] stride 9
    __shared__ float bc[256];          // [l][q]
    int blk = blockIdx.x;              // 1024 = b x 512 chunks
    int b = blk >> 9, c = blk & 511;
    int l0 = c * LC;
    int t = threadIdx.x;               // = d in scan phase
    bc[t] = BCp[((size_t)(b*NC + c))*256 + t];
    float Av[16];
    {
        const float4* Ap = (const float4*)(Alog + t*DSTATE);
        #pragma unroll
        for (int q=0;q<4;++q){
            float4 a = Ap[q];
            Av[q*4]   = -__expf(a.x);
            Av[q*4+1] = -__expf(a.y);
            Av[q*4+2] = -__expf(a.z);
            Av[q*4+3] = -__expf(a.w);
        }
    }
    // s-major coalesced Iw reads: 16 independent 256B-contiguous loads
    float h[16];
    {
        const float* Ip = Iw + ((size_t)(b*NC + c))*4096 + t;
        #pragma unroll
        for (int s=0;s<16;++s) h[s] = Ip[s*256];
    }
    // batched independent loads: 8 float2 (dt,xc) + 8 scalar z
    float2 dx2[LC];
    float  zv[LC];
    {
        const float2* pkb = pk2 + ((size_t)(b*Lseq + l0))*DIN + t;
        const float* zsp  = zs  + ((size_t)(b*Lseq + l0))*DIN + t;
        #pragma unroll
        for (int l=0;l<LC;++l){ dx2[l] = pkb[l*DIN]; zv[l] = zsp[l*DIN]; }
    }
    float Dd = Dv[t];
    __syncthreads();
    #pragma unroll
    for (int l=0;l<LC;++l){
        float dtl = dx2[l].x, xcv = dx2[l].y;
        float dx  = dtl*xcv;
        const float4* Bv = (const float4*)&bc[l*32];
        const float4* Cv = (const float4*)&bc[l*32 + 16];
        float4 B0 = Bv[0], B1 = Bv[1], B2 = Bv[2], B3 = Bv[3];
        float4 C0 = Cv[0], C1 = Cv[1], C2 = Cv[2], C3 = Cv[3];
        float y = 0.f;
        #define ST3(i, bval, cval) { float dA = __expf(dtl*Av[i]); h[i] = fmaf(dA, h[i], dx*(bval)); y = fmaf(h[i], (cval), y); }
        ST3(0,B0.x,C0.x) ST3(1,B0.y,C0.y) ST3(2,B0.z,C0.z) ST3(3,B0.w,C0.w)
        ST3(4,B1.x,C1.x) ST3(5,B1.y,C1.y) ST3(6,B1.z,C1.z) ST3(7,B1.w,C1.w)
        ST3(8,B2.x,C2.x) ST3(9,B2.y,C2.y) ST3(10,B2.z,C2.z) ST3(11,B2.w,C2.w)
        ST3(12,B3.x,C3.x) ST3(13,B3.y,C3.y) ST3(14,B3.z,C3.z) ST3(15,B3.w,C3.w)
        #undef ST3
        ysm[t*9 + l] = (y + Dd*xcv)*zv[l];
    }
    __syncthreads();
    // ---- out_proj: 8l x 128c tile. lg = t>>5 -> one l; cg = t&31 -> 4 c ----
    int lg = t >> 5, cg = t & 31;
    int c0 = cg*4;
    float a0=0.f, a1=0.f, a2=0.f, a3=0.f;
    #pragma unroll 8
    for (int k=0;k<DIN;++k){
        float yv = ysm[k*9 + lg];
        float4 wv = *(const float4*)&Wout[k*OUTC + c0];
        a0 = fmaf(yv, wv.x, a0);
        a1 = fmaf(yv, wv.y, a1);
        a2 = fmaf(yv, wv.z, a2);
        a3 = fmaf(yv, wv.w, a3);
    }
    float4 gm = *(const float4*)&lng[c0];
    float4 bt = *(const float4*)&lnb[c0];
    {
        float rs = a0+a1+a2+a3;
        #pragma unroll
        for (int m=16;m>0;m>>=1) rs += __shfl_xor(rs, m, 64);
        float mu = rs * (1.f/128.f);
        float d0 = a0-mu, d1 = a1-mu, d2 = a2-mu, d3 = a3-mu;
        float sq = d0*d0+d1*d1+d2*d2+d3*d3;
        #pragma unroll
        for (int m=16;m>0;m>>=1) sq += __shfl_xor(sq, m, 64);
        float rstd = rsqrtf(sq * (1.f/128.f) + 1e-5f);
        os[(c0+0)*9 + lg] = d0*rstd*gm.x + bt.x;
        os[(c0+1)*9 + lg] = d1*rstd*gm.y + bt.y;
        os[(c0+2)*9 + lg] = d2*rstd*gm.z + bt.z;
        os[(c0+3)*9 + lg] = d3*rstd*gm.w + bt.w;
    }
    __syncthreads();
    // ---- store: cc = t>>1, sel = t&1 -> 4 consecutive l (16B) per lane ----
    {
        int cc = t >> 1, sel = t & 1;
        const float* ip = &os[cc*9 + sel*4];
        float v0 = ip[0], v1 = ip[1], v2 = ip[2], v3 = ip[3];
        float* op = out + ((size_t)(b*OUTC + cc))*Lseq + l0 + sel*4;
        *(float4*)op = make_float4(v0, v1, v2, v3);
    }
}

extern "C" void kernel_launch(void* const* d_in, const int* in_sizes, int n_in,
                              void* d_out, int out_size, void* d_ws, size_t ws_size,
                              hipStream_t stream) {
    const float* x1    = (const float*)d_in[0];
    const float* Win   = (const float*)d_in[1];
    const float* convw = (const float*)d_in[2];
    const float* convb = (const float*)d_in[3];
    const float* Wx    = (const float*)d_in[4];
    const float* Wdt   = (const float*)d_in[5];
    const float* bdt   = (const float*)d_in[6];
    const float* Alog  = (const float*)d_in[7];
    const float* Dv    = (const float*)d_in[8];
    const float* Wout  = (const float*)d_in[9];
    const float* lng   = (const float*)d_in[10];
    const float* lnb   = (const float*)d_in[11];
    float* out = (float*)d_out;

    float* ws  = (float*)d_ws;
    float* xin = ws;                        // 2,097,152 floats (8 MB)
    float* zs  = xin + 2097152;             // 2,097,152 floats (8 MB)
    float2* pk2 = (float2*)(zs + 2097152);  // 2,097,152 float2 (16 MB): {dt, xc}
    float2* PSw = (float2*)(pk2 + 2097152); // 4,194,304 float2 (32 MB)
    float* Iw  = (float*)(PSw + 4194304);   // 4,194,304 floats (16 MB)
    float* BCp = Iw + 4194304;              //   262,144 floats (1 MB)   total ~81 MB

    k_inproj    <<<1024, 256, 0, stream>>>(x1, Win, xin, zs);
    k_conv_scan1<<<1024, 256, 0, stream>>>(xin, convw, convb, Wx, Wdt, bdt, Alog,
                                           pk2, BCp, PSw);
    k_scan2     <<<32,   256, 0, stream>>>(PSw, Iw);
    k_scan3out  <<<1024, 256, 0, stream>>>(pk2, zs, BCp, Alog, Dv, Iw,
                                           Wout, lng, lnb, out);
}

// Round 9
// 205.035 us; speedup vs baseline: 1.2617x; 1.1930x over previous
//
#include <hip/hip_runtime.h>
#include <math.h>

#define B_ 2
#define DMODEL 128
#define DIN 256
#define DSTATE 16
#define DTR 8
#define OUTC 128
#define Lseq 4096
#define NC 512          // chunks per batch
#define LC 8            // timesteps per chunk

__device__ __forceinline__ float siluf(float x){ return x / (1.f + __expf(-x)); }

// zs  layout: float  at (b*Lseq + l)*DIN + d                  (planar, coalesced)
// pk2 layout: float2 {dt, xc} at (b*Lseq + l)*DIN + d         (written once, coalesced)
// BCp layout: BCp[(b*NC + c)*256 + l*32 + q], q<16: B else C  (l local 0..7)
// PSw layout: float2 at (b*NC + c)*4096 + s*256 + d           (s-major: full-line stores)
// Iw  layout: float  at (b*NC + c)*4096 + s*256 + d           (state entering chunk c)

// ---------------- Kernel A: in_proj; 1024 blocks = b x colhalf x 256 l-tiles of 16 ------------------------
__global__ __launch_bounds__(256, 4) void k_inproj(const float* __restrict__ x1,
        const float* __restrict__ Win, float* __restrict__ xin, float* __restrict__ zs){
    __shared__ float xt[16*DMODEL];             // xt[c*16+p]
    int blk = blockIdx.x;
    int b  = blk >> 9;
    int ch = (blk >> 8) & 1;                    // 0: xin cols, 1: z cols
    int lc = blk & 255;
    int l0 = lc * 16;
    int t = threadIdx.x;
    const float* xb = x1 + (size_t)b * DMODEL * Lseq;
    #pragma unroll
    for (int i = 0; i < 8; ++i){
        int e = t + i*256;
        int c = e >> 4, p = e & 15;
        xt[e] = xb[(size_t)c*Lseq + l0 + p];
    }
    __syncthreads();
    float acc[16];
    #pragma unroll
    for (int p=0;p<16;++p) acc[p]=0.f;
    const float* wcol = Win + ch*256 + t;
    for (int k=0;k<DMODEL;++k){
        float w = wcol[k*512];
        #pragma unroll
        for (int p=0;p<16;++p) acc[p] = fmaf(xt[k*16 + p], w, acc[p]);
    }
    if (ch == 0){
        #pragma unroll
        for (int p=0;p<16;++p)
            xin[((size_t)(b*Lseq + l0 + p))*DIN + t] = acc[p];
    } else {
        #pragma unroll
        for (int p=0;p<16;++p)
            zs[((size_t)(b*Lseq + l0 + p))*DIN + t] = siluf(acc[p]);
    }
}

// ---------------- Kernel B: conv+silu, x_proj (split-d), dt_proj, fused scan pass 1; 8 l per block --------
// __launch_bounds__(256,2): 256-VGPR budget so P/S/Av arrays stay in registers (128 cap caused
// 67MB of scratch spill traffic -> 150MB excess HBM; see round-8 post-mortem).
__global__ __launch_bounds__(256, 2) void k_conv_scan1(const float* __restrict__ xin,
        const float* __restrict__ convw, const float* __restrict__ convb,
        const float* __restrict__ Wx, const float* __restrict__ Wdt,
        const float* __restrict__ bdt, const float* __restrict__ Alog,
        float2* __restrict__ pk2, float* __restrict__ BCp, float2* __restrict__ PSw){
    __shared__ float xcs[LC*257];       // [l][d]
    __shared__ float part[4*LC*40];     // [dq][l][j]
    __shared__ float xdbl[LC*40];       // [l][j]
    int blk = blockIdx.x;               // 1024 = b x 512 chunks
    int b = blk >> 9, c = blk & 511;
    int l0 = c * LC;
    int t = threadIdx.x;                // = d in conv/dt/scan phases

    // ---- conv + silu: rows l0-3 .. l0+7 ----
    float w0 = convw[t*4+0], w1 = convw[t*4+1], w2 = convw[t*4+2], w3 = convw[t*4+3];
    float bb = convb[t];
    const float* xinb = xin + ((size_t)(b*Lseq + l0))*DIN + t;
    float r[11];
    if (l0 == 0){ r[0]=r[1]=r[2]=0.f; }
    else {
        r[0] = xinb[-3*DIN]; r[1] = xinb[-2*DIN]; r[2] = xinb[-1*DIN];
    }
    #pragma unroll
    for (int i=0;i<8;++i) r[3+i] = xinb[i*DIN];
    #pragma unroll
    for (int l=0;l<LC;++l){
        float acc = bb;
        acc = fmaf(r[l],   w0, acc);
        acc = fmaf(r[l+1], w1, acc);
        acc = fmaf(r[l+2], w2, acc);
        acc = fmaf(r[l+3], w3, acc);
        xcs[l*257 + t] = siluf(acc);
    }
    __syncthreads();

    // ---- x_proj with split-d: dq = quarter of d-range ----
    {
        int dq = t >> 6;
        int lg = (t >> 3) & 7;
        int jg = t & 7;
        int j0 = jg * 5;
        float a0=0.f, a1=0.f, a2=0.f, a3=0.f, a4=0.f;
        const float* xrow = xcs + lg*257 + dq*64;
        const float* wbase = Wx + (size_t)dq*64*40 + j0;
        #pragma unroll 8
        for (int dd = 0; dd < 64; ++dd){
            float xv = xrow[dd];
            const float* wr = wbase + dd*40;
            a0 = fmaf(xv, wr[0], a0);
            a1 = fmaf(xv, wr[1], a1);
            a2 = fmaf(xv, wr[2], a2);
            a3 = fmaf(xv, wr[3], a3);
            a4 = fmaf(xv, wr[4], a4);
        }
        float* po = part + dq*320 + lg*40 + j0;
        po[0]=a0; po[1]=a1; po[2]=a2; po[3]=a3; po[4]=a4;
    }
    __syncthreads();
    for (int o = t; o < 320; o += 256)
        xdbl[o] = part[o] + part[320+o] + part[640+o] + part[960+o];
    __syncthreads();

    // ---- dt_proj + softplus + scan pass 1 (one 8-l chunk); write {dt,xc} packed, coalesced ----
    {
        float wd[DTR];
        #pragma unroll
        for (int rr=0;rr<DTR;++rr) wd[rr] = Wdt[rr*DIN + t];
        float bv = bdt[t];
        float Av[16];
        {
            const float4* Ap = (const float4*)(Alog + t*DSTATE);
            #pragma unroll
            for (int q=0;q<4;++q){
                float4 a = Ap[q];
                Av[q*4]   = -__expf(a.x);
                Av[q*4+1] = -__expf(a.y);
                Av[q*4+2] = -__expf(a.z);
                Av[q*4+3] = -__expf(a.w);
            }
        }
        float P[16], S[16];
        #pragma unroll
        for (int s=0;s<16;++s){ P[s]=1.f; S[s]=0.f; }
        float2* pkb = pk2 + ((size_t)(b*Lseq + l0))*DIN + t;
        #pragma unroll
        for (int l=0;l<LC;++l){
            float a = bv;
            #pragma unroll
            for (int rr=0;rr<DTR;++rr) a = fmaf(xdbl[l*40 + rr], wd[rr], a);
            float dtv = (a > 20.f) ? a : log1pf(__expf(a));
            float xcv = xcs[l*257 + t];
            pkb[l*DIN] = make_float2(dtv, xcv);
            float dx  = dtv*xcv;
            const float4* Bv = (const float4*)&xdbl[l*40 + DTR];
            float4 B0 = Bv[0], B1 = Bv[1], B2 = Bv[2], B3 = Bv[3];
            #define ST1(i, bval) { float dA = __expf(dtv*Av[i]); P[i] *= dA; S[i] = fmaf(dA, S[i], dx*(bval)); }
            ST1(0,B0.x) ST1(1,B0.y) ST1(2,B0.z) ST1(3,B0.w)
            ST1(4,B1.x) ST1(5,B1.y) ST1(6,B1.z) ST1(7,B1.w)
            ST1(8,B2.x) ST1(9,B2.y) ST1(10,B2.z) ST1(11,B2.w)
            ST1(12,B3.x) ST1(13,B3.y) ST1(14,B3.z) ST1(15,B3.w)
            #undef ST1
        }
        // s-major, full-line coalesced stores: 2KB contiguous per block per s
        float2* ps = PSw + ((size_t)(b*NC + c))*4096 + t;
        #pragma unroll
        for (int s=0;s<16;++s) ps[s*256] = make_float2(P[s], S[s]);
    }
    // ---- B/C extraction: 8 l x 32 ----
    {
        int l = t >> 5, q = t & 31;
        BCp[((size_t)(b*NC + c))*256 + t] = xdbl[l*40 + DTR + q];
    }
}

// ---------------- Kernel C: pass 2, serial chunk combine, coalesced streams -------------------------------
__global__ __launch_bounds__(256, 4) void k_scan2(const float2* __restrict__ PSw,
        float* __restrict__ Iw){
    int g = blockIdx.x*256 + threadIdx.x;  // 8192 channels
    int b = g >> 12;
    int r = g & 4095;
    float H = 0.f;
    #pragma unroll 8
    for (int c=0;c<NC;++c){
        size_t idx = ((size_t)(b*NC + c))*4096 + r;
        float2 ps = PSw[idx];
        Iw[idx] = H;
        H = fmaf(ps.x, H, ps.y);
    }
}

// ---------------- Kernel D: fused scan pass 3 + out_proj + LayerNorm + NCHW store; 8 l per block ----------
// __launch_bounds__(256,2): same spill fix as k_conv_scan1.
__global__ __launch_bounds__(256, 2) void k_scan3out(const float2* __restrict__ pk2,
        const float* __restrict__ zs,
        const float* __restrict__ BCp, const float* __restrict__ Alog,
        const float* __restrict__ Dv, const float* __restrict__ Iw,
        const float* __restrict__ Wout, const float* __restrict__ lng,
        const float* __restrict__ lnb, float* __restrict__ out){
    __shared__ float ysm[256*9 + 8];   // [d][l] stride 9
    __shared__ float os[128*9 + 8];    // [c][l] stride 9
    __shared__ float bc[256];          // [l][q]
    int blk = blockIdx.x;              // 1024 = b x 512 chunks
    int b = blk >> 9, c = blk & 511;
    int l0 = c * LC;
    int t = threadIdx.x;               // = d in scan phase
    bc[t] = BCp[((size_t)(b*NC + c))*256 + t];
    float Av[16];
    {
        const float4* Ap = (const float4*)(Alog + t*DSTATE);
        #pragma unroll
        for (int q=0;q<4;++q){
            float4 a = Ap[q];
            Av[q*4]   = -__expf(a.x);
            Av[q*4+1] = -__expf(a.y);
            Av[q*4+2] = -__expf(a.z);
            Av[q*4+3] = -__expf(a.w);
        }
    }
    // s-major coalesced Iw reads: 16 independent 1KB-contiguous loads
    float h[16];
    {
        const float* Ip = Iw + ((size_t)(b*NC + c))*4096 + t;
        #pragma unroll
        for (int s=0;s<16;++s) h[s] = Ip[s*256];
    }
    // batched independent loads: 8 float2 (dt,xc) + 8 scalar z
    float2 dx2[LC];
    float  zv[LC];
    {
        const float2* pkb = pk2 + ((size_t)(b*Lseq + l0))*DIN + t;
        const float* zsp  = zs  + ((size_t)(b*Lseq + l0))*DIN + t;
        #pragma unroll
        for (int l=0;l<LC;++l){ dx2[l] = pkb[l*DIN]; zv[l] = zsp[l*DIN]; }
    }
    float Dd = Dv[t];
    __syncthreads();
    #pragma unroll
    for (int l=0;l<LC;++l){
        float dtl = dx2[l].x, xcv = dx2[l].y;
        float dx  = dtl*xcv;
        const float4* Bv = (const float4*)&bc[l*32];
        const float4* Cv = (const float4*)&bc[l*32 + 16];
        float4 B0 = Bv[0], B1 = Bv[1], B2 = Bv[2], B3 = Bv[3];
        float4 C0 = Cv[0], C1 = Cv[1], C2 = Cv[2], C3 = Cv[3];
        float y = 0.f;
        #define ST3(i, bval, cval) { float dA = __expf(dtl*Av[i]); h[i] = fmaf(dA, h[i], dx*(bval)); y = fmaf(h[i], (cval), y); }
        ST3(0,B0.x,C0.x) ST3(1,B0.y,C0.y) ST3(2,B0.z,C0.z) ST3(3,B0.w,C0.w)
        ST3(4,B1.x,C1.x) ST3(5,B1.y,C1.y) ST3(6,B1.z,C1.z) ST3(7,B1.w,C1.w)
        ST3(8,B2.x,C2.x) ST3(9,B2.y,C2.y) ST3(10,B2.z,C2.z) ST3(11,B2.w,C2.w)
        ST3(12,B3.x,C3.x) ST3(13,B3.y,C3.y) ST3(14,B3.z,C3.z) ST3(15,B3.w,C3.w)
        #undef ST3
        ysm[t*9 + l] = (y + Dd*xcv)*zv[l];
    }
    __syncthreads();
    // ---- out_proj: 8l x 128c tile. lg = t>>5 -> one l; cg = t&31 -> 4 c ----
    int lg = t >> 5, cg = t & 31;
    int c0 = cg*4;
    float a0=0.f, a1=0.f, a2=0.f, a3=0.f;
    #pragma unroll 8
    for (int k=0;k<DIN;++k){
        float yv = ysm[k*9 + lg];
        float4 wv = *(const float4*)&Wout[k*OUTC + c0];
        a0 = fmaf(yv, wv.x, a0);
        a1 = fmaf(yv, wv.y, a1);
        a2 = fmaf(yv, wv.z, a2);
        a3 = fmaf(yv, wv.w, a3);
    }
    float4 gm = *(const float4*)&lng[c0];
    float4 bt = *(const float4*)&lnb[c0];
    {
        float rs = a0+a1+a2+a3;
        #pragma unroll
        for (int m=16;m>0;m>>=1) rs += __shfl_xor(rs, m, 64);
        float mu = rs * (1.f/128.f);
        float d0 = a0-mu, d1 = a1-mu, d2 = a2-mu, d3 = a3-mu;
        float sq = d0*d0+d1*d1+d2*d2+d3*d3;
        #pragma unroll
        for (int m=16;m>0;m>>=1) sq += __shfl_xor(sq, m, 64);
        float rstd = rsqrtf(sq * (1.f/128.f) + 1e-5f);
        os[(c0+0)*9 + lg] = d0*rstd*gm.x + bt.x;
        os[(c0+1)*9 + lg] = d1*rstd*gm.y + bt.y;
        os[(c0+2)*9 + lg] = d2*rstd*gm.z + bt.z;
        os[(c0+3)*9 + lg] = d3*rstd*gm.w + bt.w;
    }
    __syncthreads();
    // ---- store: cc = t>>1, sel = t&1 -> 4 consecutive l (16B) per lane ----
    {
        int cc = t >> 1, sel = t & 1;
        const float* ip = &os[cc*9 + sel*4];
        float v0 = ip[0], v1 = ip[1], v2 = ip[2], v3 = ip[3];
        float* op = out + ((size_t)(b*OUTC + cc))*Lseq + l0 + sel*4;
        *(float4*)op = make_float4(v0, v1, v2, v3);
    }
}

extern "C" void kernel_launch(void* const* d_in, const int* in_sizes, int n_in,
                              void* d_out, int out_size, void* d_ws, size_t ws_size,
                              hipStream_t stream) {
    const float* x1    = (const float*)d_in[0];
    const float* Win   = (const float*)d_in[1];
    const float* convw = (const float*)d_in[2];
    const float* convb = (const float*)d_in[3];
    const float* Wx    = (const float*)d_in[4];
    const float* Wdt   = (const float*)d_in[5];
    const float* bdt   = (const float*)d_in[6];
    const float* Alog  = (const float*)d_in[7];
    const float* Dv    = (const float*)d_in[8];
    const float* Wout  = (const float*)d_in[9];
    const float* lng   = (const float*)d_in[10];
    const float* lnb   = (const float*)d_in[11];
    float* out = (float*)d_out;

    float* ws  = (float*)d_ws;
    float* xin = ws;                        // 2,097,152 floats (8 MB)
    float* zs  = xin + 2097152;             // 2,097,152 floats (8 MB)
    float2* pk2 = (float2*)(zs + 2097152);  // 2,097,152 float2 (16 MB): {dt, xc}
    float2* PSw = (float2*)(pk2 + 2097152); // 4,194,304 float2 (32 MB)
    float* Iw  = (float*)(PSw + 4194304);   // 4,194,304 floats (16 MB)
    float* BCp = Iw + 4194304;              //   262,144 floats (1 MB)   total ~81 MB

    k_inproj    <<<1024, 256, 0, stream>>>(x1, Win, xin, zs);
    k_conv_scan1<<<1024, 256, 0, stream>>>(xin, convw, convb, Wx, Wdt, bdt, Alog,
                                           pk2, BCp, PSw);
    k_scan2     <<<32,   256, 0, stream>>>(PSw, Iw);
    k_scan3out  <<<1024, 256, 0, stream>>>(pk2, zs, BCp, Alog, Dv, Iw,
                                           Wout, lng, lnb, out);
}

// Round 10
// 201.630 us; speedup vs baseline: 1.2830x; 1.0169x over previous
//
#include <hip/hip_runtime.h>
#include <math.h>

#define B_ 2
#define DMODEL 128
#define DIN 256
#define DSTATE 16
#define DTR 8
#define OUTC 128
#define Lseq 4096
#define NC 512          // chunks per batch
#define LC 8            // timesteps per chunk

__device__ __forceinline__ float siluf(float x){ return x / (1.f + __expf(-x)); }

// zs  layout: float  at (b*Lseq + l)*DIN + d                  (planar, coalesced)
// pk2 layout: float2 {dt, xc} at (b*Lseq + l)*DIN + d         (written once, coalesced)
// BCp layout: BCp[(b*NC + c)*256 + l*32 + q], q<16: B else C  (l local 0..7)
// PSw layout: float2 at (b*NC + c)*4096 + s*256 + d           (s-major: full-line stores)
// Iw  layout: float  at (b*NC + c)*4096 + s*256 + d           (state entering chunk c)

// ---------------- Kernel A: in_proj; 1024 blocks = b x colhalf x 256 l-tiles of 16 ------------------------
__global__ __launch_bounds__(256, 4) void k_inproj(const float* __restrict__ x1,
        const float* __restrict__ Win, float* __restrict__ xin, float* __restrict__ zs){
    __shared__ float xt[16*DMODEL];             // xt[c*16+p]
    int blk = blockIdx.x;
    int b  = blk >> 9;
    int ch = (blk >> 8) & 1;                    // 0: xin cols, 1: z cols
    int lc = blk & 255;
    int l0 = lc * 16;
    int t = threadIdx.x;
    const float* xb = x1 + (size_t)b * DMODEL * Lseq;
    #pragma unroll
    for (int i = 0; i < 8; ++i){
        int e = t + i*256;
        int c = e >> 4, p = e & 15;
        xt[e] = xb[(size_t)c*Lseq + l0 + p];
    }
    __syncthreads();
    float acc[16];
    #pragma unroll
    for (int p=0;p<16;++p) acc[p]=0.f;
    const float* wcol = Win + ch*256 + t;
    for (int k=0;k<DMODEL;++k){
        float w = wcol[k*512];
        #pragma unroll
        for (int p=0;p<16;++p) acc[p] = fmaf(xt[k*16 + p], w, acc[p]);
    }
    if (ch == 0){
        #pragma unroll
        for (int p=0;p<16;++p)
            xin[((size_t)(b*Lseq + l0 + p))*DIN + t] = acc[p];
    } else {
        #pragma unroll
        for (int p=0;p<16;++p)
            zs[((size_t)(b*Lseq + l0 + p))*DIN + t] = siluf(acc[p]);
    }
}

// ---------------- Kernel B: conv+silu, x_proj (split-d), dt_proj, fused scan pass 1; 8 l per block --------
// __launch_bounds__(256,2): 256-VGPR budget so P/S/Av arrays stay in registers (128 cap caused
// 67MB of scratch spill traffic -> 150MB excess HBM; see round-8 post-mortem).
__global__ __launch_bounds__(256, 2) void k_conv_scan1(const float* __restrict__ xin,
        const float* __restrict__ convw, const float* __restrict__ convb,
        const float* __restrict__ Wx, const float* __restrict__ Wdt,
        const float* __restrict__ bdt, const float* __restrict__ Alog,
        float2* __restrict__ pk2, float* __restrict__ BCp, float2* __restrict__ PSw){
    __shared__ float xcs[LC*257];       // [l][d]
    __shared__ float part[4*LC*40];     // [dq][l][j]
    __shared__ float xdbl[LC*40];       // [l][j]
    int blk = blockIdx.x;               // 1024 = b x 512 chunks
    int b = blk >> 9, c = blk & 511;
    int l0 = c * LC;
    int t = threadIdx.x;                // = d in conv/dt/scan phases

    // ---- conv + silu: rows l0-3 .. l0+7 ----
    float w0 = convw[t*4+0], w1 = convw[t*4+1], w2 = convw[t*4+2], w3 = convw[t*4+3];
    float bb = convb[t];
    const float* xinb = xin + ((size_t)(b*Lseq + l0))*DIN + t;
    float r[11];
    if (l0 == 0){ r[0]=r[1]=r[2]=0.f; }
    else {
        r[0] = xinb[-3*DIN]; r[1] = xinb[-2*DIN]; r[2] = xinb[-1*DIN];
    }
    #pragma unroll
    for (int i=0;i<8;++i) r[3+i] = xinb[i*DIN];
    #pragma unroll
    for (int l=0;l<LC;++l){
        float acc = bb;
        acc = fmaf(r[l],   w0, acc);
        acc = fmaf(r[l+1], w1, acc);
        acc = fmaf(r[l+2], w2, acc);
        acc = fmaf(r[l+3], w3, acc);
        xcs[l*257 + t] = siluf(acc);
    }
    __syncthreads();

    // ---- x_proj with split-d: dq = quarter of d-range ----
    {
        int dq = t >> 6;
        int lg = (t >> 3) & 7;
        int jg = t & 7;
        int j0 = jg * 5;
        float a0=0.f, a1=0.f, a2=0.f, a3=0.f, a4=0.f;
        const float* xrow = xcs + lg*257 + dq*64;
        const float* wbase = Wx + (size_t)dq*64*40 + j0;
        #pragma unroll 8
        for (int dd = 0; dd < 64; ++dd){
            float xv = xrow[dd];
            const float* wr = wbase + dd*40;
            a0 = fmaf(xv, wr[0], a0);
            a1 = fmaf(xv, wr[1], a1);
            a2 = fmaf(xv, wr[2], a2);
            a3 = fmaf(xv, wr[3], a3);
            a4 = fmaf(xv, wr[4], a4);
        }
        float* po = part + dq*320 + lg*40 + j0;
        po[0]=a0; po[1]=a1; po[2]=a2; po[3]=a3; po[4]=a4;
    }
    __syncthreads();
    for (int o = t; o < 320; o += 256)
        xdbl[o] = part[o] + part[320+o] + part[640+o] + part[960+o];
    __syncthreads();

    // ---- dt_proj + softplus + scan pass 1 (one 8-l chunk); write {dt,xc} packed, coalesced ----
    {
        float wd[DTR];
        #pragma unroll
        for (int rr=0;rr<DTR;++rr) wd[rr] = Wdt[rr*DIN + t];
        float bv = bdt[t];
        float Av[16];
        {
            const float4* Ap = (const float4*)(Alog + t*DSTATE);
            #pragma unroll
            for (int q=0;q<4;++q){
                float4 a = Ap[q];
                Av[q*4]   = -__expf(a.x);
                Av[q*4+1] = -__expf(a.y);
                Av[q*4+2] = -__expf(a.z);
                Av[q*4+3] = -__expf(a.w);
            }
        }
        float P[16], S[16];
        #pragma unroll
        for (int s=0;s<16;++s){ P[s]=1.f; S[s]=0.f; }
        float2* pkb = pk2 + ((size_t)(b*Lseq + l0))*DIN + t;
        #pragma unroll
        for (int l=0;l<LC;++l){
            float a = bv;
            #pragma unroll
            for (int rr=0;rr<DTR;++rr) a = fmaf(xdbl[l*40 + rr], wd[rr], a);
            float dtv = (a > 20.f) ? a : log1pf(__expf(a));
            float xcv = xcs[l*257 + t];
            pkb[l*DIN] = make_float2(dtv, xcv);
            float dx  = dtv*xcv;
            const float4* Bv = (const float4*)&xdbl[l*40 + DTR];
            float4 B0 = Bv[0], B1 = Bv[1], B2 = Bv[2], B3 = Bv[3];
            #define ST1(i, bval) { float dA = __expf(dtv*Av[i]); P[i] *= dA; S[i] = fmaf(dA, S[i], dx*(bval)); }
            ST1(0,B0.x) ST1(1,B0.y) ST1(2,B0.z) ST1(3,B0.w)
            ST1(4,B1.x) ST1(5,B1.y) ST1(6,B1.z) ST1(7,B1.w)
            ST1(8,B2.x) ST1(9,B2.y) ST1(10,B2.z) ST1(11,B2.w)
            ST1(12,B3.x) ST1(13,B3.y) ST1(14,B3.z) ST1(15,B3.w)
            #undef ST1
        }
        // s-major, full-line coalesced stores: 2KB contiguous per block per s
        float2* ps = PSw + ((size_t)(b*NC + c))*4096 + t;
        #pragma unroll
        for (int s=0;s<16;++s) ps[s*256] = make_float2(P[s], S[s]);
    }
    // ---- B/C extraction: 8 l x 32 ----
    {
        int l = t >> 5, q = t & 31;
        BCp[((size_t)(b*NC + c))*256 + t] = xdbl[l*40 + DTR + q];
    }
}

// ---------------- Kernel C: pass 2, serial chunk combine, coalesced streams -------------------------------
__global__ __launch_bounds__(256, 4) void k_scan2(const float2* __restrict__ PSw,
        float* __restrict__ Iw){
    int g = blockIdx.x*256 + threadIdx.x;  // 8192 channels
    int b = g >> 12;
    int r = g & 4095;
    float H = 0.f;
    #pragma unroll 16
    for (int c=0;c<NC;++c){
        size_t idx = ((size_t)(b*NC + c))*4096 + r;
        float2 ps = PSw[idx];
        Iw[idx] = H;
        H = fmaf(ps.x, H, ps.y);
    }
}

// ---------------- Kernel D: fused scan pass 3 + out_proj + LayerNorm + NCHW store; 8 l per block ----------
// All per-l loop inputs staged into LDS with batched coalesced float4 loads BEFORE the scan loop:
// round-9 showed the compiler (VGPR_Count=60) sinks register-staged global loads back into the
// serial loop -> dependent-latency chain. LDS staging is a phase the scheduler can't unwind.
__global__ __launch_bounds__(256, 4) void k_scan3out(const float2* __restrict__ pk2,
        const float* __restrict__ zs,
        const float* __restrict__ BCp, const float* __restrict__ Alog,
        const float* __restrict__ Dv, const float* __restrict__ Iw,
        const float* __restrict__ Wout, const float* __restrict__ lng,
        const float* __restrict__ lnb, float* __restrict__ out){
    __shared__ float2 pks[LC*256];     // [l][d] {dt,xc}  16 KB
    __shared__ float  zss[LC*256];     // [l][d]           8 KB
    __shared__ float ysm[256*9 + 8];   // [d][l] stride 9  9.2 KB
    __shared__ float os[128*9 + 8];    // [c][l] stride 9  4.6 KB
    __shared__ float bc[256];          // [l][q]           1 KB
    int blk = blockIdx.x;              // 1024 = b x 512 chunks
    int b = blk >> 9, c = blk & 511;
    int l0 = c * LC;
    int t = threadIdx.x;               // = d in scan phase

    // ---- batched coalesced staging (all loads independent, issued up front) ----
    {
        const float4* src = (const float4*)(pk2 + ((size_t)(b*Lseq + l0))*DIN);  // 1024 float4
        float4* pd = (float4*)pks;
        #pragma unroll
        for (int i=0;i<4;++i) pd[i*256 + t] = src[i*256 + t];
        const float4* zsrc = (const float4*)(zs + ((size_t)(b*Lseq + l0))*DIN);  // 512 float4
        float4* zd = (float4*)zss;
        #pragma unroll
        for (int i=0;i<2;++i) zd[i*256 + t] = zsrc[i*256 + t];
    }
    bc[t] = BCp[((size_t)(b*NC + c))*256 + t];
    float h[16];
    {
        const float* Ip = Iw + ((size_t)(b*NC + c))*4096 + t;   // s-major: 16 coalesced 1KB runs
        #pragma unroll
        for (int s=0;s<16;++s) h[s] = Ip[s*256];
    }
    float Av[16];
    {
        const float4* Ap = (const float4*)(Alog + t*DSTATE);
        #pragma unroll
        for (int q=0;q<4;++q){
            float4 a = Ap[q];
            Av[q*4]   = -__expf(a.x);
            Av[q*4+1] = -__expf(a.y);
            Av[q*4+2] = -__expf(a.z);
            Av[q*4+3] = -__expf(a.w);
        }
    }
    float Dd = Dv[t];
    __syncthreads();

    // ---- scan loop: LDS-only inputs ----
    #pragma unroll
    for (int l=0;l<LC;++l){
        float2 dxv = pks[l*256 + t];       // ds_read_b64, 2-way aliasing (free)
        float  zv  = zss[l*256 + t];
        float dtl = dxv.x, xcv = dxv.y;
        float dx  = dtl*xcv;
        const float4* Bv = (const float4*)&bc[l*32];
        const float4* Cv = (const float4*)&bc[l*32 + 16];
        float4 B0 = Bv[0], B1 = Bv[1], B2 = Bv[2], B3 = Bv[3];
        float4 C0 = Cv[0], C1 = Cv[1], C2 = Cv[2], C3 = Cv[3];
        float y = 0.f;
        #define ST3(i, bval, cval) { float dA = __expf(dtl*Av[i]); h[i] = fmaf(dA, h[i], dx*(bval)); y = fmaf(h[i], (cval), y); }
        ST3(0,B0.x,C0.x) ST3(1,B0.y,C0.y) ST3(2,B0.z,C0.z) ST3(3,B0.w,C0.w)
        ST3(4,B1.x,C1.x) ST3(5,B1.y,C1.y) ST3(6,B1.z,C1.z) ST3(7,B1.w,C1.w)
        ST3(8,B2.x,C2.x) ST3(9,B2.y,C2.y) ST3(10,B2.z,C2.z) ST3(11,B2.w,C2.w)
        ST3(12,B3.x,C3.x) ST3(13,B3.y,C3.y) ST3(14,B3.z,C3.z) ST3(15,B3.w,C3.w)
        #undef ST3
        ysm[t*9 + l] = (y + Dd*xcv)*zv;
    }
    __syncthreads();
    // ---- out_proj: 8l x 128c tile. lg = t>>5 -> one l; cg = t&31 -> 4 c ----
    int lg = t >> 5, cg = t & 31;
    int c0 = cg*4;
    float a0=0.f, a1=0.f, a2=0.f, a3=0.f;
    #pragma unroll 16
    for (int k=0;k<DIN;++k){
        float yv = ysm[k*9 + lg];
        float4 wv = *(const float4*)&Wout[k*OUTC + c0];
        a0 = fmaf(yv, wv.x, a0);
        a1 = fmaf(yv, wv.y, a1);
        a2 = fmaf(yv, wv.z, a2);
        a3 = fmaf(yv, wv.w, a3);
    }
    float4 gm = *(const float4*)&lng[c0];
    float4 bt = *(const float4*)&lnb[c0];
    {
        float rs = a0+a1+a2+a3;
        #pragma unroll
        for (int m=16;m>0;m>>=1) rs += __shfl_xor(rs, m, 64);
        float mu = rs * (1.f/128.f);
        float d0 = a0-mu, d1 = a1-mu, d2 = a2-mu, d3 = a3-mu;
        float sq = d0*d0+d1*d1+d2*d2+d3*d3;
        #pragma unroll
        for (int m=16;m>0;m>>=1) sq += __shfl_xor(sq, m, 64);
        float rstd = rsqrtf(sq * (1.f/128.f) + 1e-5f);
        os[(c0+0)*9 + lg] = d0*rstd*gm.x + bt.x;
        os[(c0+1)*9 + lg] = d1*rstd*gm.y + bt.y;
        os[(c0+2)*9 + lg] = d2*rstd*gm.z + bt.z;
        os[(c0+3)*9 + lg] = d3*rstd*gm.w + bt.w;
    }
    __syncthreads();
    // ---- store: cc = t>>1, sel = t&1 -> 4 consecutive l (16B) per lane ----
    {
        int cc = t >> 1, sel = t & 1;
        const float* ip = &os[cc*9 + sel*4];
        float v0 = ip[0], v1 = ip[1], v2 = ip[2], v3 = ip[3];
        float* op = out + ((size_t)(b*OUTC + cc))*Lseq + l0 + sel*4;
        *(float4*)op = make_float4(v0, v1, v2, v3);
    }
}

extern "C" void kernel_launch(void* const* d_in, const int* in_sizes, int n_in,
                              void* d_out, int out_size, void* d_ws, size_t ws_size,
                              hipStream_t stream) {
    const float* x1    = (const float*)d_in[0];
    const float* Win   = (const float*)d_in[1];
    const float* convw = (const float*)d_in[2];
    const float* convb = (const float*)d_in[3];
    const float* Wx    = (const float*)d_in[4];
    const float* Wdt   = (const float*)d_in[5];
    const float* bdt   = (const float*)d_in[6];
    const float* Alog  = (const float*)d_in[7];
    const float* Dv    = (const float*)d_in[8];
    const float* Wout  = (const float*)d_in[9];
    const float* lng   = (const float*)d_in[10];
    const float* lnb   = (const float*)d_in[11];
    float* out = (float*)d_out;

    float* ws  = (float*)d_ws;
    float* xin = ws;                        // 2,097,152 floats (8 MB)
    float* zs  = xin + 2097152;             // 2,097,152 floats (8 MB)
    float2* pk2 = (float2*)(zs + 2097152);  // 2,097,152 float2 (16 MB): {dt, xc}
    float2* PSw = (float2*)(pk2 + 2097152); // 4,194,304 float2 (32 MB)
    float* Iw  = (float*)(PSw + 4194304);   // 4,194,304 floats (16 MB)
    float* BCp = Iw + 4194304;              //   262,144 floats (1 MB)   total ~81 MB

    k_inproj    <<<1024, 256, 0, stream>>>(x1, Win, xin, zs);
    k_conv_scan1<<<1024, 256, 0, stream>>>(xin, convw, convb, Wx, Wdt, bdt, Alog,
                                           pk2, BCp, PSw);
    k_scan2     <<<32,   256, 0, stream>>>(PSw, Iw);
    k_scan3out  <<<1024, 256, 0, stream>>>(pk2, zs, BCp, Alog, Dv, Iw,
                                           Wout, lng, lnb, out);
}